// Round 7
// baseline (530.005 us; speedup 1.0000x reference)
//
#include <hip/hip_runtime.h>
#include <hip/hip_bf16.h>

#define B_ 2
#define N_ 2048
#define C_ 1024
#define H_ 16
#define D_ 64
#define F_ 4096
#define M_ 4096  // B_*N_

typedef __attribute__((ext_vector_type(8))) short bf16x8;
typedef __attribute__((ext_vector_type(4))) float f32x4;

__device__ inline unsigned short f2bf(float f) {
  unsigned int u = __float_as_uint(f);
  u = (u + 0x7FFFu + ((u >> 16) & 1u)) >> 16;
  return (unsigned short)u;
}

// ---------------- all-weights fp32 -> bf16 in one launch ---------------------
__global__ __launch_bounds__(256)
void cvt_all(const float4* __restrict__ s0, const float4* __restrict__ s1,
             const float4* __restrict__ s2, const float4* __restrict__ s3,
             const float4* __restrict__ s4, const float4* __restrict__ s5,
             ushort4* __restrict__ d0, ushort4* __restrict__ d1,
             ushort4* __restrict__ d2, ushort4* __restrict__ d3,
             ushort4* __restrict__ d4, ushort4* __restrict__ d5) {
  int b = blockIdx.x;
  const float4* s; ushort4* d; int i;
  if      (b < 1024) { s = s0; d = d0; i = b * 256 + threadIdx.x; }
  else if (b < 2048) { s = s1; d = d1; i = (b - 1024) * 256 + threadIdx.x; }
  else if (b < 3072) { s = s2; d = d2; i = (b - 2048) * 256 + threadIdx.x; }
  else if (b < 4096) { s = s3; d = d3; i = (b - 3072) * 256 + threadIdx.x; }
  else if (b < 8192) { s = s4; d = d4; i = (b - 4096) * 256 + threadIdx.x; }
  else               { s = s5; d = d5; i = (b - 8192) * 256 + threadIdx.x; }
  float4 f = s[i];
  ushort4 o;
  o.x = f2bf(f.x); o.y = f2bf(f.y); o.z = f2bf(f.z); o.w = f2bf(f.w);
  d[i] = o;
}

// ---------------- LayerNorm: fp32 in -> bf16 out ------------------------------
__global__ __launch_bounds__(256)
void ln_kernel(const float* __restrict__ x, const float* __restrict__ g,
               const float* __restrict__ b, unsigned short* __restrict__ out) {
  __shared__ float red[8];
  const int row = blockIdx.x;
  const int t = threadIdx.x;
  const float4 xv = *(const float4*)(x + row * 1024 + t * 4);
  float s  = xv.x + xv.y + xv.z + xv.w;
  float sq = xv.x * xv.x + xv.y * xv.y + xv.z * xv.z + xv.w * xv.w;
  #pragma unroll
  for (int off = 32; off >= 1; off >>= 1) {
    s  += __shfl_down(s, off);
    sq += __shfl_down(sq, off);
  }
  const int lane = t & 63, wave = t >> 6;
  if (lane == 0) { red[wave * 2] = s; red[wave * 2 + 1] = sq; }
  __syncthreads();
  float ts = red[0] + red[2] + red[4] + red[6];
  float tq = red[1] + red[3] + red[5] + red[7];
  float mean = ts * (1.0f / 1024.0f);
  float var  = tq * (1.0f / 1024.0f) - mean * mean;
  float rstd = rsqrtf(var + 1e-6f);
  float xs[4] = {xv.x, xv.y, xv.z, xv.w};
  #pragma unroll
  for (int i = 0; i < 4; i++) {
    int c = t * 4 + i;
    float y = (xs[i] - mean) * rstd * g[c] + b[c];
    out[row * 1024 + c] = f2bf(y);
  }
}

// ---------------- GEMM v7: A via LDS-dbuf DMA, B via register prefetch -------
// out[m,n] = sum_k A[m,k]*Bw[n,k].  Block 128x128, wave-tile 64x64.
// A staged with global_load_lds (double-buffered, 1 barrier/iter).
// B-fragments read per-lane straight from global (weights L2/L1-hot across
// m-blocks), prefetched one K-iter ahead into registers -> LDS traffic halved.
// MODE 1: +bias +resid -> fp32   [O-proj]
// MODE 2: +bias, exact GELU -> bf16 [MLP1]
// MODE 3: +bias +resid -> fp32   [MLP2 -> d_out]
template<int MODE, int NIT>
__global__ __launch_bounds__(256)
void gemm_bt(const unsigned short* __restrict__ A,
             const unsigned short* __restrict__ Bw,
             int Nout,
             const float* __restrict__ bias,
             const float* __restrict__ resid,
             unsigned short* __restrict__ out_bf,
             float* __restrict__ out_f32) {
  const int K = NIT * 64;
  __shared__ unsigned short sA[2][128 * 64];
  const int t = threadIdx.x;
  const int wave = t >> 6, lane = t & 63;
  const int quad = lane >> 4, l16 = lane & 15;
  const int wm = (wave & 1) * 64, wn = (wave >> 1) * 64;
  const int m0 = blockIdx.y * 128, n0 = blockIdx.x * 128;

  f32x4 acc[4][4];
  #pragma unroll
  for (int i = 0; i < 4; i++)
    #pragma unroll
    for (int j = 0; j < 4; j++) acc[i][j] = (f32x4){0.f, 0.f, 0.f, 0.f};

  const unsigned short* gA = A + (m0 + (t >> 3)) * K + (t & 7) * 8;
  const unsigned short* gB = Bw + (n0 + wn + l16) * K + quad * 8;

  bf16x8 bfr[2][8];   // [phase][kk*4+j]

  auto stageA = [&](int kt, int buf) {
    unsigned short* lA = &sA[buf][(wave * 8) * 64];
    #pragma unroll
    for (int i = 0; i < 4; i++)
      __builtin_amdgcn_global_load_lds((const unsigned int*)(gA + (32 * i) * K + kt * 64),
                                       (unsigned int*)(lA + 32 * i * 64), 16, 0, 0);
  };
  #define LOADB(kt, ph)                                                        \
    _Pragma("unroll")                                                          \
    for (int j = 0; j < 4; j++)                                                \
      _Pragma("unroll")                                                        \
      for (int kk = 0; kk < 2; kk++)                                           \
        bfr[ph][kk * 4 + j] = *(const bf16x8*)(gB + (j * 16) * K + (kt) * 64 + kk * 32);
  #define COMPUTE(ph)                                                          \
    _Pragma("unroll")                                                          \
    for (int kk = 0; kk < 2; kk++) {                                           \
      bf16x8 af[4];                                                            \
      _Pragma("unroll")                                                        \
      for (int i = 0; i < 4; i++)                                              \
        af[i] = *(const bf16x8*)(&sA[ph][(wm + i * 16 + l16) * 64 + kk * 32 + quad * 8]); \
      _Pragma("unroll")                                                        \
      for (int i = 0; i < 4; i++)                                              \
        _Pragma("unroll")                                                      \
        for (int j = 0; j < 4; j++)                                            \
          acc[i][j] = __builtin_amdgcn_mfma_f32_16x16x32_bf16(af[i], bfr[ph][kk * 4 + j], acc[i][j], 0, 0, 0); \
    }

  LOADB(0, 0);
  stageA(0, 0);
  __syncthreads();
  for (int kt = 0; kt < NIT; kt += 2) {
    if (kt + 1 < NIT) { stageA(kt + 1, 1); LOADB(kt + 1, 1); }
    COMPUTE(0);
    __syncthreads();
    if (kt + 1 < NIT) {
      if (kt + 2 < NIT) { stageA(kt + 2, 0); LOADB(kt + 2, 0); }
      COMPUTE(1);
      __syncthreads();
    }
  }
  #undef LOADB
  #undef COMPUTE

  #pragma unroll
  for (int i = 0; i < 4; i++) {
    #pragma unroll
    for (int j = 0; j < 4; j++) {
      int col = n0 + wn + j * 16 + l16;
      #pragma unroll
      for (int r = 0; r < 4; r++) {
        int row = m0 + wm + i * 16 + quad * 4 + r;
        float v = acc[i][j][r];
        if (MODE == 1 || MODE == 3) {
          out_f32[row * Nout + col] = v + bias[col] + resid[row * Nout + col];
        } else {  // MODE 2
          v += bias[col];
          float gl = 0.5f * v * (1.0f + erff(v * 0.70710678118654752f));
          out_bf[row * Nout + col] = f2bf(gl);
        }
      }
    }
  }
}

// ---------------- QKV GEMM (same v7 structure), fused bias+RoPE+split --------
// q/k: (B*H, N, D) RoPE'd (q pre-scaled by D^-0.5). v: transposed (B*H, D, N).
__global__ __launch_bounds__(256)
void gemm_qkv(const unsigned short* __restrict__ A,
              const unsigned short* __restrict__ Bw,
              const float* __restrict__ bq, const float* __restrict__ bk,
              const float* __restrict__ bv,
              const float* __restrict__ rc, const float* __restrict__ rs,
              unsigned short* __restrict__ qo, unsigned short* __restrict__ ko,
              unsigned short* __restrict__ vt) {
  const int K = C_;
  const int NIT = 16;
  __shared__ unsigned short sA[2][128 * 64];
  const int t = threadIdx.x;
  const int wave = t >> 6, lane = t & 63;
  const int quad = lane >> 4, l16 = lane & 15;
  const int wm = (wave & 1) * 64, wn = (wave >> 1) * 64;
  const int m0 = blockIdx.y * 128, n0 = blockIdx.x * 128;

  f32x4 acc[4][4];
  #pragma unroll
  for (int i = 0; i < 4; i++)
    #pragma unroll
    for (int j = 0; j < 4; j++) acc[i][j] = (f32x4){0.f, 0.f, 0.f, 0.f};

  const unsigned short* gA = A + (m0 + (t >> 3)) * K + (t & 7) * 8;
  const unsigned short* gB = Bw + (n0 + wn + l16) * K + quad * 8;

  bf16x8 bfr[2][8];

  auto stageA = [&](int kt, int buf) {
    unsigned short* lA = &sA[buf][(wave * 8) * 64];
    #pragma unroll
    for (int i = 0; i < 4; i++)
      __builtin_amdgcn_global_load_lds((const unsigned int*)(gA + (32 * i) * K + kt * 64),
                                       (unsigned int*)(lA + 32 * i * 64), 16, 0, 0);
  };
  #define LOADB(kt, ph)                                                        \
    _Pragma("unroll")                                                          \
    for (int j = 0; j < 4; j++)                                                \
      _Pragma("unroll")                                                        \
      for (int kk = 0; kk < 2; kk++)                                           \
        bfr[ph][kk * 4 + j] = *(const bf16x8*)(gB + (j * 16) * K + (kt) * 64 + kk * 32);
  #define COMPUTE(ph)                                                          \
    _Pragma("unroll")                                                          \
    for (int kk = 0; kk < 2; kk++) {                                           \
      bf16x8 af[4];                                                            \
      _Pragma("unroll")                                                        \
      for (int i = 0; i < 4; i++)                                              \
        af[i] = *(const bf16x8*)(&sA[ph][(wm + i * 16 + l16) * 64 + kk * 32 + quad * 8]); \
      _Pragma("unroll")                                                        \
      for (int i = 0; i < 4; i++)                                              \
        _Pragma("unroll")                                                      \
        for (int j = 0; j < 4; j++)                                            \
          acc[i][j] = __builtin_amdgcn_mfma_f32_16x16x32_bf16(af[i], bfr[ph][kk * 4 + j], acc[i][j], 0, 0, 0); \
    }

  LOADB(0, 0);
  stageA(0, 0);
  __syncthreads();
  for (int kt = 0; kt < NIT; kt += 2) {
    if (kt + 1 < NIT) { stageA(kt + 1, 1); LOADB(kt + 1, 1); }
    COMPUTE(0);
    __syncthreads();
    if (kt + 1 < NIT) {
      if (kt + 2 < NIT) { stageA(kt + 2, 0); LOADB(kt + 2, 0); }
      COMPUTE(1);
      __syncthreads();
    }
  }
  #undef LOADB
  #undef COMPUTE

  const int rgn = blockIdx.x >> 3;                 // 0=q, 1=k, 2=v
  const int c0 = (blockIdx.x & 7) * 128;

  if (rgn == 2) {
    // V^T epilogue: lane owns (d, 4 consecutive n) -> one 8B store
    #pragma unroll
    for (int i = 0; i < 4; i++) {
      int row0 = m0 + wm + i * 16 + quad * 4;      // token of r=0
      int bidx = row0 >> 11, n0r = row0 & 2047;
      #pragma unroll
      for (int j = 0; j < 4; j++) {
        int d = j * 16 + l16;
        int c = c0 + wn + d;
        int h = c >> 6;
        float bb = bv[c];
        __hip_bfloat162 p01 = __float22bfloat162_rn(float2{acc[i][j][0] + bb, acc[i][j][1] + bb});
        __hip_bfloat162 p23 = __float22bfloat162_rn(float2{acc[i][j][2] + bb, acc[i][j][3] + bb});
        unsigned int u01, u23;
        __builtin_memcpy(&u01, &p01, 4);
        __builtin_memcpy(&u23, &p23, 4);
        *(uint2*)(vt + (((bidx * 16 + h) * 64) + (c & 63)) * 2048 + n0r) = make_uint2(u01, u23);
      }
    }
  } else {
    const float* bias = (rgn == 0) ? bq : bk;
    unsigned short* outp = (rgn == 0) ? qo : ko;
    #pragma unroll
    for (int i = 0; i < 4; i++) {
      #pragma unroll
      for (int r = 0; r < 4; r++) {
        int row = m0 + wm + i * 16 + quad * 4 + r;
        int bidx = row >> 11, n = row & 2047;
        #pragma unroll
        for (int j = 0; j < 4; j++) {
          int d = j * 16 + l16;
          int c = c0 + wn + d;
          int h = c >> 6;
          int oi = ((bidx * 16 + h) * 2048 + n) * 64 + d;
          float val = acc[i][j][r] + bias[c];
          float pv  = acc[i][j ^ 2][r] + bias[c ^ 32];
          float rot = (j < 2) ? -pv : pv;          // rotate_half
          float y = val * rc[n * 64 + d] + rot * rs[n * 64 + d];
          if (rgn == 0) y *= 0.125f;               // fold D^-0.5 into q
          outp[oi] = f2bf(y);
        }
      }
    }
  }
}

// ---------------- Flash attention v6 (unchanged from round 6) ----------------
__global__ __launch_bounds__(256)
void flash_attn(const unsigned short* __restrict__ q,
                const unsigned short* __restrict__ k,
                const unsigned short* __restrict__ vt,
                unsigned short* __restrict__ o) {
  __shared__ unsigned short sK[2][64 * 64];
  __shared__ unsigned short sVt[2][64 * 64];
  __shared__ unsigned short sPt[2][4][16 * 72];
  const int t = threadIdx.x;
  const int wave = t >> 6, lane = t & 63;
  const int quad = lane >> 4, l16 = lane & 15;
  const int bh = blockIdx.y;
  const int qb = blockIdx.x;            // 16 blocks of 128 q-rows
  const int base = bh * (N_ * D_);

  bf16x8 qa[2][2];
  #pragma unroll
  for (int qt = 0; qt < 2; qt++) {
    int qrow = qb * 128 + wave * 32 + qt * 16 + l16;
    #pragma unroll
    for (int kk = 0; kk < 2; kk++)
      qa[qt][kk] = *(const bf16x8*)(q + base + qrow * D_ + kk * 32 + quad * 8);
  }
  float l_i[2] = {0.f, 0.f};
  f32x4 o_acc[2][4];
  #pragma unroll
  for (int qt = 0; qt < 2; qt++)
    #pragma unroll
    for (int dt = 0; dt < 4; dt++) o_acc[qt][dt] = (f32x4){0.f, 0.f, 0.f, 0.f};

  const unsigned short* gK  = k  + base + (t >> 3) * 64 + (t & 7) * 8;
  const unsigned short* gVt = vt + bh * (64 * 2048) + (t >> 3) * 2048 + (t & 7) * 8;

  auto stage = [&](int kt, int buf) {
    unsigned short* lK = &sK[buf][(wave * 8) * 64];
    unsigned short* lV = &sVt[buf][(wave * 8) * 64];
    #pragma unroll
    for (int i = 0; i < 2; i++) {
      __builtin_amdgcn_global_load_lds((const unsigned int*)(gK + (kt * 64 + 32 * i) * 64),
                                       (unsigned int*)(lK + 32 * i * 64), 16, 0, 0);
      __builtin_amdgcn_global_load_lds((const unsigned int*)(gVt + 32 * i * 2048 + kt * 64),
                                       (unsigned int*)(lV + 32 * i * 64), 16, 0, 0);
    }
  };
  stage(0, 0);
  __syncthreads();

  for (int kt = 0; kt < N_ / 64; kt++) {
    const int cur = kt & 1;
    if (kt < N_ / 64 - 1) stage(kt + 1, cur ^ 1);

    f32x4 s_acc[2][4];
    #pragma unroll
    for (int nt = 0; nt < 4; nt++) {
      bf16x8 kb0 = *(const bf16x8*)(&sK[cur][(nt * 16 + l16) * 64 + quad * 8]);
      bf16x8 kb1 = *(const bf16x8*)(&sK[cur][(nt * 16 + l16) * 64 + 32 + quad * 8]);
      #pragma unroll
      for (int qt = 0; qt < 2; qt++) {
        f32x4 a = (f32x4){0.f, 0.f, 0.f, 0.f};
        a = __builtin_amdgcn_mfma_f32_16x16x32_bf16(kb0, qa[qt][0], a, 0, 0, 0);
        a = __builtin_amdgcn_mfma_f32_16x16x32_bf16(kb1, qa[qt][1], a, 0, 0, 0);
        s_acc[qt][nt] = a;
      }
    }
    #pragma unroll
    for (int qt = 0; qt < 2; qt++) {
      float rsum = 0.f;
      #pragma unroll
      for (int nt = 0; nt < 4; nt++)
        #pragma unroll
        for (int r = 0; r < 4; r++) {
          float p = __expf(s_acc[qt][nt][r]);
          s_acc[qt][nt][r] = p;
          rsum += p;
        }
      rsum += __shfl_xor(rsum, 16);
      rsum += __shfl_xor(rsum, 32);
      l_i[qt] += rsum;
      #pragma unroll
      for (int nt = 0; nt < 4; nt++) {
        __hip_bfloat162 p01 = __float22bfloat162_rn(float2{s_acc[qt][nt][0], s_acc[qt][nt][1]});
        __hip_bfloat162 p23 = __float22bfloat162_rn(float2{s_acc[qt][nt][2], s_acc[qt][nt][3]});
        unsigned int u01, u23;
        __builtin_memcpy(&u01, &p01, 4);
        __builtin_memcpy(&u23, &p23, 4);
        *(uint2*)(&sPt[qt][wave][l16 * 72 + nt * 16 + quad * 4]) = make_uint2(u01, u23);
      }
    }
    __asm__ volatile("s_waitcnt lgkmcnt(0)" ::: "memory");
    bf16x8 pt[2][2];
    #pragma unroll
    for (int qt = 0; qt < 2; qt++) {
      pt[qt][0] = *(const bf16x8*)(&sPt[qt][wave][l16 * 72 + quad * 8]);
      pt[qt][1] = *(const bf16x8*)(&sPt[qt][wave][l16 * 72 + 32 + quad * 8]);
    }
    #pragma unroll
    for (int dt = 0; dt < 4; dt++) {
      int d0 = dt * 16 + l16;
      bf16x8 va0 = *(const bf16x8*)(&sVt[cur][d0 * 64 + quad * 8]);
      bf16x8 va1 = *(const bf16x8*)(&sVt[cur][d0 * 64 + 32 + quad * 8]);
      #pragma unroll
      for (int qt = 0; qt < 2; qt++) {
        o_acc[qt][dt] = __builtin_amdgcn_mfma_f32_16x16x32_bf16(va0, pt[qt][0], o_acc[qt][dt], 0, 0, 0);
        o_acc[qt][dt] = __builtin_amdgcn_mfma_f32_16x16x32_bf16(va1, pt[qt][1], o_acc[qt][dt], 0, 0, 0);
      }
    }
    __syncthreads();
  }

  const int b = bh >> 4, h = bh & 15;
  #pragma unroll
  for (int qt = 0; qt < 2; qt++) {
    const float inv = 1.0f / l_i[qt];
    const int tok = b * N_ + qb * 128 + wave * 32 + qt * 16 + l16;
    #pragma unroll
    for (int dt = 0; dt < 4; dt++) {
      __hip_bfloat162 p01 = __float22bfloat162_rn(float2{o_acc[qt][dt][0] * inv, o_acc[qt][dt][1] * inv});
      __hip_bfloat162 p23 = __float22bfloat162_rn(float2{o_acc[qt][dt][2] * inv, o_acc[qt][dt][3] * inv});
      unsigned int u01, u23;
      __builtin_memcpy(&u01, &p01, 4);
      __builtin_memcpy(&u23, &p23, 4);
      int col = h * 64 + dt * 16 + quad * 4;
      *(uint2*)(o + tok * C_ + col) = make_uint2(u01, u23);
    }
  }
}

// ---------------- launcher ---------------------------------------------------
extern "C" void kernel_launch(void* const* d_in, const int* in_sizes, int n_in,
                              void* d_out, int out_size, void* d_ws, size_t ws_size,
                              hipStream_t stream) {
  const float* x   = (const float*)d_in[0];
  const float* rc  = (const float*)d_in[1];
  const float* rs  = (const float*)d_in[2];
  const float* g1  = (const float*)d_in[3];
  const float* be1 = (const float*)d_in[4];
  const float* Wq  = (const float*)d_in[5];
  const float* bq  = (const float*)d_in[6];
  const float* Wk  = (const float*)d_in[7];
  const float* bk  = (const float*)d_in[8];
  const float* Wv  = (const float*)d_in[9];
  const float* bv  = (const float*)d_in[10];
  const float* Wo  = (const float*)d_in[11];
  const float* bo  = (const float*)d_in[12];
  const float* g2  = (const float*)d_in[13];
  const float* be2 = (const float*)d_in[14];
  const float* W1  = (const float*)d_in[15];
  const float* b1m = (const float*)d_in[16];
  const float* W2  = (const float*)d_in[17];
  const float* b2m = (const float*)d_in[18];
  float* out = (float*)d_out;

  char* ws = (char*)d_ws;
  unsigned short* wqkv = (unsigned short*)(ws + 0);           // 6 MB
  unsigned short* wo   = (unsigned short*)(ws + 6291456);     // 2 MB
  unsigned short* w1   = (unsigned short*)(ws + 8388608);     // 8 MB
  unsigned short* w2   = (unsigned short*)(ws + 16777216);    // 8 MB
  unsigned short* h1   = (unsigned short*)(ws + 25165824);    // 8 MB (also h2)
  unsigned short* qa   = (unsigned short*)(ws + 33554432);    // 8 MB
  unsigned short* ka   = (unsigned short*)(ws + 41943040);    // 8 MB
  unsigned short* va   = (unsigned short*)(ws + 50331648);    // 8 MB (V^T: B*H x D x N)
  unsigned short* ao   = (unsigned short*)(ws + 58720256);    // 8 MB
  float*          x1   = (float*)(ws + 67108864);             // 16 MB
  unsigned short* u    = (unsigned short*)(ws + 33554432);    // overlays qa..ao (dead by MLP1)

  cvt_all<<<12288, 256, 0, stream>>>(
      (const float4*)Wq, (const float4*)Wk, (const float4*)Wv, (const float4*)Wo,
      (const float4*)W1, (const float4*)W2,
      (ushort4*)wqkv, (ushort4*)(wqkv + 1048576), (ushort4*)(wqkv + 2097152),
      (ushort4*)wo, (ushort4*)w1, (ushort4*)w2);

  ln_kernel<<<4096, 256, 0, stream>>>(x, g1, be1, h1);
  gemm_qkv<<<dim3(24, 32), 256, 0, stream>>>(h1, wqkv, bq, bk, bv, rc, rs, qa, ka, va);
  flash_attn<<<dim3(16, 32), 256, 0, stream>>>(qa, ka, va, ao);
  gemm_bt<1, 16><<<dim3(8, 32), 256, 0, stream>>>(ao, wo, 1024, bo, x, nullptr, x1);
  ln_kernel<<<4096, 256, 0, stream>>>(x1, g2, be2, h1);
  gemm_bt<2, 16><<<dim3(32, 32), 256, 0, stream>>>(h1, w1, 4096, b1m, nullptr, u, nullptr);
  gemm_bt<3, 64><<<dim3(8, 32), 256, 0, stream>>>(u, w2, 1024, b2m, x1, nullptr, out);
}

// Round 8
// 428.725 us; speedup vs baseline: 1.2362x; 1.2362x over previous
//
#include <hip/hip_runtime.h>
#include <hip/hip_bf16.h>

#define B_ 2
#define N_ 2048
#define C_ 1024
#define H_ 16
#define D_ 64
#define F_ 4096
#define M_ 4096  // B_*N_

typedef __attribute__((ext_vector_type(8))) short bf16x8;
typedef __attribute__((ext_vector_type(4))) float f32x4;

__device__ inline unsigned short f2bf(float f) {
  unsigned int u = __float_as_uint(f);
  u = (u + 0x7FFFu + ((u >> 16) & 1u)) >> 16;
  return (unsigned short)u;
}

// ---------------- all-weights fp32 -> bf16 in one launch ---------------------
__global__ __launch_bounds__(256)
void cvt_all(const float4* __restrict__ s0, const float4* __restrict__ s1,
             const float4* __restrict__ s2, const float4* __restrict__ s3,
             const float4* __restrict__ s4, const float4* __restrict__ s5,
             ushort4* __restrict__ d0, ushort4* __restrict__ d1,
             ushort4* __restrict__ d2, ushort4* __restrict__ d3,
             ushort4* __restrict__ d4, ushort4* __restrict__ d5) {
  int b = blockIdx.x;
  const float4* s; ushort4* d; int i;
  if      (b < 1024) { s = s0; d = d0; i = b * 256 + threadIdx.x; }
  else if (b < 2048) { s = s1; d = d1; i = (b - 1024) * 256 + threadIdx.x; }
  else if (b < 3072) { s = s2; d = d2; i = (b - 2048) * 256 + threadIdx.x; }
  else if (b < 4096) { s = s3; d = d3; i = (b - 3072) * 256 + threadIdx.x; }
  else if (b < 8192) { s = s4; d = d4; i = (b - 4096) * 256 + threadIdx.x; }
  else               { s = s5; d = d5; i = (b - 8192) * 256 + threadIdx.x; }
  float4 f = s[i];
  ushort4 o;
  o.x = f2bf(f.x); o.y = f2bf(f.y); o.z = f2bf(f.z); o.w = f2bf(f.w);
  d[i] = o;
}

// ---------------- LayerNorm: fp32 in -> bf16 out ------------------------------
__global__ __launch_bounds__(256)
void ln_kernel(const float* __restrict__ x, const float* __restrict__ g,
               const float* __restrict__ b, unsigned short* __restrict__ out) {
  __shared__ float red[8];
  const int row = blockIdx.x;
  const int t = threadIdx.x;
  const float4 xv = *(const float4*)(x + row * 1024 + t * 4);
  float s  = xv.x + xv.y + xv.z + xv.w;
  float sq = xv.x * xv.x + xv.y * xv.y + xv.z * xv.z + xv.w * xv.w;
  #pragma unroll
  for (int off = 32; off >= 1; off >>= 1) {
    s  += __shfl_down(s, off);
    sq += __shfl_down(sq, off);
  }
  const int lane = t & 63, wave = t >> 6;
  if (lane == 0) { red[wave * 2] = s; red[wave * 2 + 1] = sq; }
  __syncthreads();
  float ts = red[0] + red[2] + red[4] + red[6];
  float tq = red[1] + red[3] + red[5] + red[7];
  float mean = ts * (1.0f / 1024.0f);
  float var  = tq * (1.0f / 1024.0f) - mean * mean;
  float rstd = rsqrtf(var + 1e-6f);
  float xs[4] = {xv.x, xv.y, xv.z, xv.w};
  #pragma unroll
  for (int i = 0; i < 4; i++) {
    int c = t * 4 + i;
    float y = (xs[i] - mean) * rstd * g[c] + b[c];
    out[row * 1024 + c] = f2bf(y);
  }
}

// ---------------- GEMM (round-6 LDS structure + XCD swizzle) -----------------
// out[m,n] = sum_k A[m,k]*Bw[n,k]. A,B staged via global_load_lds width=16.
// XCD swizzle: id%8 picks a fixed set of npc n-blocks -> B tile stays in that
// XCD's L2 (<=1 MB), DMA latency ~200cyc instead of ~900.
// MODE 1: +bias +resid -> fp32   [O-proj]
// MODE 2: +bias, tanh-GELU -> bf16 [MLP1]  (max |dGELU| ~3e-4 vs exact erf)
// MODE 3: +bias +resid -> fp32   [MLP2 -> d_out]
template<int MODE, int BN>
__global__ __launch_bounds__(256)
void gemm_bt(const unsigned short* __restrict__ A,
             const unsigned short* __restrict__ Bw,
             int K, int Nout, int npc,
             const float* __restrict__ bias,
             const float* __restrict__ resid,
             unsigned short* __restrict__ out_bf,
             float* __restrict__ out_f32) {
  constexpr int NJ = BN / 32;
  __shared__ unsigned short sA[128 * 64];
  __shared__ unsigned short sB[BN * 64];
  const int t = threadIdx.x;
  const int wave = t >> 6, lane = t & 63;
  const int quad = lane >> 4, l16 = lane & 15;
  const int wm = (wave & 1) * 64, wn = (wave >> 1) * (BN / 2);
  // XCD-aware swizzle
  const int id = blockIdx.y * gridDim.x + blockIdx.x;
  const int xcd = id & 7, r_ = id >> 3;
  const int n_blk = xcd * npc + r_ % npc;
  const int m_blk = r_ / npc;
  const int m0 = m_blk * 128, n0 = n_blk * BN;

  f32x4 acc[4][NJ];
  #pragma unroll
  for (int i = 0; i < 4; i++)
    #pragma unroll
    for (int j = 0; j < NJ; j++) acc[i][j] = (f32x4){0.f, 0.f, 0.f, 0.f};

  const unsigned short* gA = A  + (m0 + (t >> 3)) * K + (t & 7) * 8;
  const unsigned short* gB = Bw + (n0 + (t >> 3)) * K + (t & 7) * 8;
  unsigned short* lA = &sA[(wave * 8) * 64];
  unsigned short* lB = &sB[(wave * 8) * 64];

  for (int k0 = 0; k0 < K; k0 += 64) {
    #pragma unroll
    for (int i = 0; i < 4; i++)
      __builtin_amdgcn_global_load_lds((const unsigned int*)(gA + (32 * i) * K + k0),
                                       (unsigned int*)(lA + 32 * i * 64), 16, 0, 0);
    #pragma unroll
    for (int i = 0; i < BN / 32; i++)
      __builtin_amdgcn_global_load_lds((const unsigned int*)(gB + (32 * i) * K + k0),
                                       (unsigned int*)(lB + 32 * i * 64), 16, 0, 0);
    __syncthreads();
    #pragma unroll
    for (int kk = 0; kk < 2; kk++) {
      bf16x8 af[4], bfr[NJ];
      #pragma unroll
      for (int i = 0; i < 4; i++)
        af[i] = *(const bf16x8*)(&sA[(wm + i * 16 + l16) * 64 + kk * 32 + quad * 8]);
      #pragma unroll
      for (int j = 0; j < NJ; j++)
        bfr[j] = *(const bf16x8*)(&sB[(wn + j * 16 + l16) * 64 + kk * 32 + quad * 8]);
      #pragma unroll
      for (int i = 0; i < 4; i++)
        #pragma unroll
        for (int j = 0; j < NJ; j++)
          acc[i][j] = __builtin_amdgcn_mfma_f32_16x16x32_bf16(af[i], bfr[j], acc[i][j], 0, 0, 0);
    }
    __syncthreads();
  }

  #pragma unroll
  for (int i = 0; i < 4; i++) {
    #pragma unroll
    for (int j = 0; j < NJ; j++) {
      int col = n0 + wn + j * 16 + l16;
      #pragma unroll
      for (int r = 0; r < 4; r++) {
        int row = m0 + wm + i * 16 + quad * 4 + r;
        float v = acc[i][j][r];
        if (MODE == 1 || MODE == 3) {
          out_f32[row * Nout + col] = v + bias[col] + resid[row * Nout + col];
        } else {  // MODE 2: tanh-form GELU (cheap: 1 exp vs ~25-op erff)
          v += bias[col];
          float w = v * (1.0f + 0.044715f * v * v);
          float gl = v / (1.0f + __expf(-1.5957691216f * w));
          out_bf[row * Nout + col] = f2bf(gl);
        }
      }
    }
  }
}

// ---------------- QKV GEMM (round-6 structure + swizzle), RoPE epilogue ------
// q/k: (B*H, N, D) RoPE'd (q pre-scaled by D^-0.5). v: transposed (B*H, D, N).
__global__ __launch_bounds__(256)
void gemm_qkv(const unsigned short* __restrict__ A,
              const unsigned short* __restrict__ Bw,
              const float* __restrict__ bq, const float* __restrict__ bk,
              const float* __restrict__ bv,
              const float* __restrict__ rc, const float* __restrict__ rs,
              unsigned short* __restrict__ qo, unsigned short* __restrict__ ko,
              unsigned short* __restrict__ vt) {
  const int K = C_;
  __shared__ unsigned short sA[128 * 64];
  __shared__ unsigned short sB[128 * 64];
  const int t = threadIdx.x;
  const int wave = t >> 6, lane = t & 63;
  const int quad = lane >> 4, l16 = lane & 15;
  const int wm = (wave & 1) * 64, wn = (wave >> 1) * 64;
  // swizzle: 24 n-blocks -> npc=3 per XCD
  const int id = blockIdx.y * gridDim.x + blockIdx.x;
  const int xcd = id & 7, r_ = id >> 3;
  const int n_blk = xcd * 3 + r_ % 3;
  const int m_blk = r_ / 3;
  const int m0 = m_blk * 128, n0 = n_blk * 128;

  f32x4 acc[4][4];
  #pragma unroll
  for (int i = 0; i < 4; i++)
    #pragma unroll
    for (int j = 0; j < 4; j++) acc[i][j] = (f32x4){0.f, 0.f, 0.f, 0.f};

  const unsigned short* gA = A  + (m0 + (t >> 3)) * K + (t & 7) * 8;
  const unsigned short* gB = Bw + (n0 + (t >> 3)) * K + (t & 7) * 8;
  unsigned short* lA = &sA[(wave * 8) * 64];
  unsigned short* lB = &sB[(wave * 8) * 64];

  for (int k0 = 0; k0 < K; k0 += 64) {
    #pragma unroll
    for (int i = 0; i < 4; i++) {
      __builtin_amdgcn_global_load_lds((const unsigned int*)(gA + (32 * i) * K + k0),
                                       (unsigned int*)(lA + 32 * i * 64), 16, 0, 0);
      __builtin_amdgcn_global_load_lds((const unsigned int*)(gB + (32 * i) * K + k0),
                                       (unsigned int*)(lB + 32 * i * 64), 16, 0, 0);
    }
    __syncthreads();
    #pragma unroll
    for (int kk = 0; kk < 2; kk++) {
      bf16x8 af[4], bfr[4];
      #pragma unroll
      for (int i = 0; i < 4; i++)
        af[i] = *(const bf16x8*)(&sA[(wm + i * 16 + l16) * 64 + kk * 32 + quad * 8]);
      #pragma unroll
      for (int j = 0; j < 4; j++)
        bfr[j] = *(const bf16x8*)(&sB[(wn + j * 16 + l16) * 64 + kk * 32 + quad * 8]);
      #pragma unroll
      for (int i = 0; i < 4; i++)
        #pragma unroll
        for (int j = 0; j < 4; j++)
          acc[i][j] = __builtin_amdgcn_mfma_f32_16x16x32_bf16(af[i], bfr[j], acc[i][j], 0, 0, 0);
    }
    __syncthreads();
  }

  const int rgn = n_blk >> 3;                 // 0=q, 1=k, 2=v
  const int c0 = (n_blk & 7) * 128;

  if (rgn == 2) {
    #pragma unroll
    for (int i = 0; i < 4; i++) {
      int row0 = m0 + wm + i * 16 + quad * 4;      // token of r=0
      int bidx = row0 >> 11, n0r = row0 & 2047;
      #pragma unroll
      for (int j = 0; j < 4; j++) {
        int d = j * 16 + l16;
        int c = c0 + wn + d;
        int h = c >> 6;
        float bb = bv[c];
        __hip_bfloat162 p01 = __float22bfloat162_rn(float2{acc[i][j][0] + bb, acc[i][j][1] + bb});
        __hip_bfloat162 p23 = __float22bfloat162_rn(float2{acc[i][j][2] + bb, acc[i][j][3] + bb});
        unsigned int u01, u23;
        __builtin_memcpy(&u01, &p01, 4);
        __builtin_memcpy(&u23, &p23, 4);
        *(uint2*)(vt + (((bidx * 16 + h) * 64) + (c & 63)) * 2048 + n0r) = make_uint2(u01, u23);
      }
    }
  } else {
    const float* bias = (rgn == 0) ? bq : bk;
    unsigned short* outp = (rgn == 0) ? qo : ko;
    #pragma unroll
    for (int i = 0; i < 4; i++) {
      #pragma unroll
      for (int r = 0; r < 4; r++) {
        int row = m0 + wm + i * 16 + quad * 4 + r;
        int bidx = row >> 11, n = row & 2047;
        #pragma unroll
        for (int j = 0; j < 4; j++) {
          int d = j * 16 + l16;
          int c = c0 + wn + d;
          int h = c >> 6;
          int oi = ((bidx * 16 + h) * 2048 + n) * 64 + d;
          float val = acc[i][j][r] + bias[c];
          float pv  = acc[i][j ^ 2][r] + bias[c ^ 32];
          float rot = (j < 2) ? -pv : pv;          // rotate_half
          float y = val * rc[n * 64 + d] + rot * rs[n * 64 + d];
          if (rgn == 0) y *= 0.125f;               // fold D^-0.5 into q
          outp[oi] = f2bf(y);
        }
      }
    }
  }
}

// ---------------- Flash attention v6 + XCD swizzle (head-local L2) -----------
__global__ __launch_bounds__(256)
void flash_attn(const unsigned short* __restrict__ q,
                const unsigned short* __restrict__ k,
                const unsigned short* __restrict__ vt,
                unsigned short* __restrict__ o) {
  __shared__ unsigned short sK[2][64 * 64];
  __shared__ unsigned short sVt[2][64 * 64];
  __shared__ unsigned short sPt[2][4][16 * 72];
  const int t = threadIdx.x;
  const int wave = t >> 6, lane = t & 63;
  const int quad = lane >> 4, l16 = lane & 15;
  // swizzle: 32 heads -> 4 per XCD (KV working set 2 MB < 4 MB L2)
  const int id = blockIdx.y * gridDim.x + blockIdx.x;
  const int bh = (id & 7) * 4 + ((id >> 3) & 3);
  const int qb = id >> 5;               // 16 blocks of 128 q-rows
  const int base = bh * (N_ * D_);

  bf16x8 qa[2][2];
  #pragma unroll
  for (int qt = 0; qt < 2; qt++) {
    int qrow = qb * 128 + wave * 32 + qt * 16 + l16;
    #pragma unroll
    for (int kk = 0; kk < 2; kk++)
      qa[qt][kk] = *(const bf16x8*)(q + base + qrow * D_ + kk * 32 + quad * 8);
  }
  float l_i[2] = {0.f, 0.f};
  f32x4 o_acc[2][4];
  #pragma unroll
  for (int qt = 0; qt < 2; qt++)
    #pragma unroll
    for (int dt = 0; dt < 4; dt++) o_acc[qt][dt] = (f32x4){0.f, 0.f, 0.f, 0.f};

  const unsigned short* gK  = k  + base + (t >> 3) * 64 + (t & 7) * 8;
  const unsigned short* gVt = vt + bh * (64 * 2048) + (t >> 3) * 2048 + (t & 7) * 8;

  auto stage = [&](int kt, int buf) {
    unsigned short* lK = &sK[buf][(wave * 8) * 64];
    unsigned short* lV = &sVt[buf][(wave * 8) * 64];
    #pragma unroll
    for (int i = 0; i < 2; i++) {
      __builtin_amdgcn_global_load_lds((const unsigned int*)(gK + (kt * 64 + 32 * i) * 64),
                                       (unsigned int*)(lK + 32 * i * 64), 16, 0, 0);
      __builtin_amdgcn_global_load_lds((const unsigned int*)(gVt + 32 * i * 2048 + kt * 64),
                                       (unsigned int*)(lV + 32 * i * 64), 16, 0, 0);
    }
  };
  stage(0, 0);
  __syncthreads();

  for (int kt = 0; kt < N_ / 64; kt++) {
    const int cur = kt & 1;
    if (kt < N_ / 64 - 1) stage(kt + 1, cur ^ 1);

    f32x4 s_acc[2][4];
    #pragma unroll
    for (int nt = 0; nt < 4; nt++) {
      bf16x8 kb0 = *(const bf16x8*)(&sK[cur][(nt * 16 + l16) * 64 + quad * 8]);
      bf16x8 kb1 = *(const bf16x8*)(&sK[cur][(nt * 16 + l16) * 64 + 32 + quad * 8]);
      #pragma unroll
      for (int qt = 0; qt < 2; qt++) {
        f32x4 a = (f32x4){0.f, 0.f, 0.f, 0.f};
        a = __builtin_amdgcn_mfma_f32_16x16x32_bf16(kb0, qa[qt][0], a, 0, 0, 0);
        a = __builtin_amdgcn_mfma_f32_16x16x32_bf16(kb1, qa[qt][1], a, 0, 0, 0);
        s_acc[qt][nt] = a;
      }
    }
    #pragma unroll
    for (int qt = 0; qt < 2; qt++) {
      float rsum = 0.f;
      #pragma unroll
      for (int nt = 0; nt < 4; nt++)
        #pragma unroll
        for (int r = 0; r < 4; r++) {
          float p = __expf(s_acc[qt][nt][r]);
          s_acc[qt][nt][r] = p;
          rsum += p;
        }
      rsum += __shfl_xor(rsum, 16);
      rsum += __shfl_xor(rsum, 32);
      l_i[qt] += rsum;
      #pragma unroll
      for (int nt = 0; nt < 4; nt++) {
        __hip_bfloat162 p01 = __float22bfloat162_rn(float2{s_acc[qt][nt][0], s_acc[qt][nt][1]});
        __hip_bfloat162 p23 = __float22bfloat162_rn(float2{s_acc[qt][nt][2], s_acc[qt][nt][3]});
        unsigned int u01, u23;
        __builtin_memcpy(&u01, &p01, 4);
        __builtin_memcpy(&u23, &p23, 4);
        *(uint2*)(&sPt[qt][wave][l16 * 72 + nt * 16 + quad * 4]) = make_uint2(u01, u23);
      }
    }
    __asm__ volatile("s_waitcnt lgkmcnt(0)" ::: "memory");
    bf16x8 pt[2][2];
    #pragma unroll
    for (int qt = 0; qt < 2; qt++) {
      pt[qt][0] = *(const bf16x8*)(&sPt[qt][wave][l16 * 72 + quad * 8]);
      pt[qt][1] = *(const bf16x8*)(&sPt[qt][wave][l16 * 72 + 32 + quad * 8]);
    }
    #pragma unroll
    for (int dt = 0; dt < 4; dt++) {
      int d0 = dt * 16 + l16;
      bf16x8 va0 = *(const bf16x8*)(&sVt[cur][d0 * 64 + quad * 8]);
      bf16x8 va1 = *(const bf16x8*)(&sVt[cur][d0 * 64 + 32 + quad * 8]);
      #pragma unroll
      for (int qt = 0; qt < 2; qt++) {
        o_acc[qt][dt] = __builtin_amdgcn_mfma_f32_16x16x32_bf16(va0, pt[qt][0], o_acc[qt][dt], 0, 0, 0);
        o_acc[qt][dt] = __builtin_amdgcn_mfma_f32_16x16x32_bf16(va1, pt[qt][1], o_acc[qt][dt], 0, 0, 0);
      }
    }
    __syncthreads();
  }

  const int b = bh >> 4, h = bh & 15;
  #pragma unroll
  for (int qt = 0; qt < 2; qt++) {
    const float inv = 1.0f / l_i[qt];
    const int tok = b * N_ + qb * 128 + wave * 32 + qt * 16 + l16;
    #pragma unroll
    for (int dt = 0; dt < 4; dt++) {
      __hip_bfloat162 p01 = __float22bfloat162_rn(float2{o_acc[qt][dt][0] * inv, o_acc[qt][dt][1] * inv});
      __hip_bfloat162 p23 = __float22bfloat162_rn(float2{o_acc[qt][dt][2] * inv, o_acc[qt][dt][3] * inv});
      unsigned int u01, u23;
      __builtin_memcpy(&u01, &p01, 4);
      __builtin_memcpy(&u23, &p23, 4);
      int col = h * 64 + dt * 16 + quad * 4;
      *(uint2*)(o + tok * C_ + col) = make_uint2(u01, u23);
    }
  }
}

// ---------------- launcher ---------------------------------------------------
extern "C" void kernel_launch(void* const* d_in, const int* in_sizes, int n_in,
                              void* d_out, int out_size, void* d_ws, size_t ws_size,
                              hipStream_t stream) {
  const float* x   = (const float*)d_in[0];
  const float* rc  = (const float*)d_in[1];
  const float* rs  = (const float*)d_in[2];
  const float* g1  = (const float*)d_in[3];
  const float* be1 = (const float*)d_in[4];
  const float* Wq  = (const float*)d_in[5];
  const float* bq  = (const float*)d_in[6];
  const float* Wk  = (const float*)d_in[7];
  const float* bk  = (const float*)d_in[8];
  const float* Wv  = (const float*)d_in[9];
  const float* bv  = (const float*)d_in[10];
  const float* Wo  = (const float*)d_in[11];
  const float* bo  = (const float*)d_in[12];
  const float* g2  = (const float*)d_in[13];
  const float* be2 = (const float*)d_in[14];
  const float* W1  = (const float*)d_in[15];
  const float* b1m = (const float*)d_in[16];
  const float* W2  = (const float*)d_in[17];
  const float* b2m = (const float*)d_in[18];
  float* out = (float*)d_out;

  char* ws = (char*)d_ws;
  unsigned short* wqkv = (unsigned short*)(ws + 0);           // 6 MB
  unsigned short* wo   = (unsigned short*)(ws + 6291456);     // 2 MB
  unsigned short* w1   = (unsigned short*)(ws + 8388608);     // 8 MB
  unsigned short* w2   = (unsigned short*)(ws + 16777216);    // 8 MB
  unsigned short* h1   = (unsigned short*)(ws + 25165824);    // 8 MB (also h2)
  unsigned short* qa   = (unsigned short*)(ws + 33554432);    // 8 MB
  unsigned short* ka   = (unsigned short*)(ws + 41943040);    // 8 MB
  unsigned short* va   = (unsigned short*)(ws + 50331648);    // 8 MB (V^T: B*H x D x N)
  unsigned short* ao   = (unsigned short*)(ws + 58720256);    // 8 MB
  float*          x1   = (float*)(ws + 67108864);             // 16 MB
  unsigned short* u    = (unsigned short*)(ws + 33554432);    // overlays qa..ao (dead by MLP1)

  cvt_all<<<12288, 256, 0, stream>>>(
      (const float4*)Wq, (const float4*)Wk, (const float4*)Wv, (const float4*)Wo,
      (const float4*)W1, (const float4*)W2,
      (ushort4*)wqkv, (ushort4*)(wqkv + 1048576), (ushort4*)(wqkv + 2097152),
      (ushort4*)wo, (ushort4*)w1, (ushort4*)w2);

  ln_kernel<<<4096, 256, 0, stream>>>(x, g1, be1, h1);
  gemm_qkv<<<dim3(24, 32), 256, 0, stream>>>(h1, wqkv, bq, bk, bv, rc, rs, qa, ka, va);
  flash_attn<<<dim3(16, 32), 256, 0, stream>>>(qa, ka, va, ao);
  gemm_bt<1, 64><<<dim3(16, 32), 256, 0, stream>>>(ao, wo, 1024, 1024, 2, bo, x, nullptr, x1);
  ln_kernel<<<4096, 256, 0, stream>>>(x1, g2, be2, h1);
  gemm_bt<2, 128><<<dim3(32, 32), 256, 0, stream>>>(h1, w1, 1024, 4096, 4, b1m, nullptr, u, nullptr);
  gemm_bt<3, 64><<<dim3(16, 32), 256, 0, stream>>>(u, w2, 4096, 1024, 2, b2m, x1, nullptr, out);
}